// Round 1
// baseline (11573.524 us; speedup 1.0000x reference)
//
#include <hip/hip_runtime.h>
#include <hip/hip_bf16.h>

using bf16x8 = __attribute__((ext_vector_type(8))) __bf16;
using f32x4  = __attribute__((ext_vector_type(4))) float;

constexpr int NB = 32;     // batch
constexpr int NS = 512;    // seq len
constexpr int NE = 512;    // embed dim
constexpr int NH = 1024;   // hidden
constexpr int NV = 5000;   // vocab
constexpr int NG = 4096;   // 4*NH (gates: i,f,g,o)

constexpr int LSTM_BLOCKS = 64;   // persistent scan: 64 blocks x 16 hidden units

// ---------- bf16 helpers (raw ushort storage) ----------
__device__ __forceinline__ float blo(unsigned u) {
    union { unsigned i; float f; } v; v.i = u << 16; return v.f;
}
__device__ __forceinline__ unsigned short f2bf(float f) {  // round-to-nearest-even
    union { float f; unsigned i; } v; v.f = f;
    unsigned r = v.i + 0x7fffu + ((v.i >> 16) & 1u);
    return (unsigned short)(r >> 16);
}
// pack 8 fp32 -> 8 bf16 (as uint4, shorts in index order, little-endian)
__device__ __forceinline__ uint4 pack8(float4 a, float4 b) {
    uint4 r;
    r.x = (unsigned)f2bf(a.x) | ((unsigned)f2bf(a.y) << 16);
    r.y = (unsigned)f2bf(a.z) | ((unsigned)f2bf(a.w) << 16);
    r.z = (unsigned)f2bf(b.x) | ((unsigned)f2bf(b.y) << 16);
    r.w = (unsigned)f2bf(b.z) | ((unsigned)f2bf(b.w) << 16);
    return r;
}

// =====================================================================
// GEMM1: xg[m, g] = sum_e emb[x[m]][e] * W_ih[g][e] + b_ih[g] + b_hh[g]
// (unchanged — verified correct)
// =====================================================================
__global__ __launch_bounds__(256) void k_embed_gemm(
    const int* __restrict__ x,
    const float* __restrict__ emb,
    const float* __restrict__ W_ih,
    const float* __restrict__ b_ih,
    const float* __restrict__ b_hh,
    unsigned short* __restrict__ xg)
{
    constexpr int BK = 32, LDP = BK + 8;
    __shared__ __align__(16) unsigned short Ash[64 * LDP];
    __shared__ __align__(16) unsigned short Bsh[64 * LDP];
    __shared__ int ids[64];

    const int tid = threadIdx.x;
    const int m0 = blockIdx.y * 64;
    const int n0 = blockIdx.x * 64;
    if (tid < 64) ids[tid] = x[m0 + tid];
    __syncthreads();

    const int wave = tid >> 6, lane = tid & 63;
    const int wm = (wave >> 1) * 32, wn = (wave & 1) * 32;
    const int fr = lane & 15, kq = lane >> 4;

    const int sr = tid >> 2;
    const int sc = (tid & 3) * 8;

    f32x4 acc[2][2] = {};

    for (int k0 = 0; k0 < NE; k0 += BK) {
        const float* ap = emb + (size_t)ids[sr] * NE + k0 + sc;
        const float* bp = W_ih + (size_t)(n0 + sr) * NE + k0 + sc;
        float4 af0 = *(const float4*)ap, af1 = *(const float4*)(ap + 4);
        float4 bf0 = *(const float4*)bp, bf1 = *(const float4*)(bp + 4);
        *(uint4*)(Ash + sr * LDP + sc) = pack8(af0, af1);
        *(uint4*)(Bsh + sr * LDP + sc) = pack8(bf0, bf1);
        __syncthreads();
        bf16x8 a0 = *(const bf16x8*)(Ash + (wm + fr) * LDP + kq * 8);
        bf16x8 a1 = *(const bf16x8*)(Ash + (wm + 16 + fr) * LDP + kq * 8);
        bf16x8 b0 = *(const bf16x8*)(Bsh + (wn + fr) * LDP + kq * 8);
        bf16x8 b1 = *(const bf16x8*)(Bsh + (wn + 16 + fr) * LDP + kq * 8);
        acc[0][0] = __builtin_amdgcn_mfma_f32_16x16x32_bf16(a0, b0, acc[0][0], 0, 0, 0);
        acc[0][1] = __builtin_amdgcn_mfma_f32_16x16x32_bf16(a0, b1, acc[0][1], 0, 0, 0);
        acc[1][0] = __builtin_amdgcn_mfma_f32_16x16x32_bf16(a1, b0, acc[1][0], 0, 0, 0);
        acc[1][1] = __builtin_amdgcn_mfma_f32_16x16x32_bf16(a1, b1, acc[1][1], 0, 0, 0);
        __syncthreads();
    }

    for (int i = 0; i < 2; ++i)
        for (int j = 0; j < 2; ++j) {
            const int row = m0 + wm + i * 16 + kq * 4;
            const int col = n0 + wn + j * 16 + fr;
            const float bias = b_ih[col] + b_hh[col];
            for (int r = 0; r < 4; ++r)
                xg[(size_t)(row + r) * NG + col] = f2bf(acc[i][j][r] + bias);
        }
}

// =====================================================================
// Persistent LSTM scan: ONE kernel for all 512 timesteps.
//  - 64 blocks x 256 threads (4 waves, 1 wave/SIMD -> 512-VGPR budget).
//  - Block owns 16 hidden units; wave w = gate w (rows w*NH + j0 + 0..15).
//  - W_hh slice lives in REGISTERS as bf16 (128 VGPR/lane), loaded ONCE.
//  - Per step: stage h_{t-1} [32,1024] bf16 global -> XOR-swizzled LDS,
//    full-K MFMA (no K-split, no reduction), fused activations,
//    c state resident in LDS, h_t -> global hs, device-scope grid barrier.
// =====================================================================
__global__ __launch_bounds__(256, 1) void k_lstm_persist(
    const unsigned short* __restrict__ xg,   // bf16 [B,S,4H]
    const float* __restrict__ W_hh,          // fp32 [4H,H]
    unsigned short* __restrict__ hs,         // bf16 [B,S,H]
    unsigned* __restrict__ bar)              // bar[0]=count, bar[1]=generation
{
    __shared__ __align__(16) unsigned short h_sh[32 * 1024];  // 64 KB, swizzled
    __shared__ float gates_sh[32 * 65];                       // [b][col] pad65
    __shared__ float c_sh[32 * 17];                           // persistent cell state

    const int tid  = threadIdx.x;
    const int wave = tid >> 6, lane = tid & 63;
    const int fr = lane & 15, kq = lane >> 4;
    const int j0 = blockIdx.x * 16;          // this block's 16 hidden units

    // ---- register-resident W_hh (bf16): wave = gate, lane col fr = unit ----
    bf16x8 bfrag[32];
    {
        const float* wrow = W_hh + (size_t)(wave * NH + j0 + fr) * NH;
#pragma unroll
        for (int ks = 0; ks < 32; ++ks) {
            const float* wp = wrow + ks * 32 + kq * 8;
            float4 w0 = *(const float4*)wp, w1 = *(const float4*)(wp + 4);
            uint4 pk = pack8(w0, w1);
            bfrag[ks] = *(bf16x8*)&pk;
        }
    }

    // ---- zero h (h_{-1}=0) and c ----
    {
        uint4 z = {0, 0, 0, 0};
#pragma unroll
        for (int r = 0; r < 16; ++r)
            *(uint4*)((char*)h_sh + r * 4096 + tid * 16) = z;
        for (int i = tid; i < 32 * 17; i += 256) c_sh[i] = 0.f;
    }
    __syncthreads();

    const int srow = tid >> 7;     // staging: waves 0/1 -> even b, 2/3 -> odd b
    const int sc16 = tid & 127;    // 16B chunk within a 2048B row
    const int swz  = (fr & 7) << 4;

    for (int t = 0; t < NS; ++t) {
        // -- xg prefetch (independent of barrier; hides under staging) --
        unsigned short xv[2][4];
#pragma unroll
        for (int p = 0; p < 2; ++p) {
            const int i = tid + p * 256, b = i & 31, u = i >> 5;
            const unsigned short* xp = xg + ((size_t)b * NS + t) * NG + j0 + u;
#pragma unroll
            for (int g = 0; g < 4; ++g) xv[p][g] = xp[g * NH];
        }

        // -- stage h_{t-1} from global into swizzled LDS --
        if (t > 0) {
            uint4 stg[16];
#pragma unroll
            for (int r = 0; r < 16; ++r) {
                const int b = r * 2 + srow;
                stg[r] = *(const uint4*)(hs + ((size_t)b * NS + (t - 1)) * NH + sc16 * 8);
            }
#pragma unroll
            for (int r = 0; r < 16; ++r) {
                const int b = r * 2 + srow;
                int off = b * 2048 + sc16 * 16;
                off ^= (b & 7) << 4;                     // same XOR as read side
                *(uint4*)((char*)h_sh + off) = stg[r];
            }
        }
        __syncthreads();

        // -- gates = h_{t-1} @ W_hh_slice^T  (full K=1024, no reduction) --
        f32x4 acc0 = {}, acc1 = {};
#pragma unroll
        for (int ks = 0; ks < 32; ++ks) {
            const int cb = ks * 64 + kq * 16;
            bf16x8 a0 = *(const bf16x8*)((const char*)h_sh + ((fr * 2048 + cb) ^ swz));
            bf16x8 a1 = *(const bf16x8*)((const char*)h_sh + (((fr + 16) * 2048 + cb) ^ swz));
            acc0 = __builtin_amdgcn_mfma_f32_16x16x32_bf16(a0, bfrag[ks], acc0, 0, 0, 0);
            acc1 = __builtin_amdgcn_mfma_f32_16x16x32_bf16(a1, bfrag[ks], acc1, 0, 0, 0);
        }

        // C/D layout: row(batch) = kq*4+r, col = fr; wave w -> cols w*16..w*16+15
#pragma unroll
        for (int r = 0; r < 4; ++r) {
            gates_sh[(kq * 4 + r) * 65 + wave * 16 + fr]      = acc0[r];
            gates_sh[(16 + kq * 4 + r) * 65 + wave * 16 + fr] = acc1[r];
        }
        __syncthreads();

        // -- activations + state update: 512 items = 32 b x 16 u, 2/thread --
#pragma unroll
        for (int p = 0; p < 2; ++p) {
            const int i = tid + p * 256, b = i & 31, u = i >> 5;
            const float gi = gates_sh[b * 65 +      u] + blo((unsigned)xv[p][0]);
            const float gf = gates_sh[b * 65 + 16 + u] + blo((unsigned)xv[p][1]);
            const float gg = gates_sh[b * 65 + 32 + u] + blo((unsigned)xv[p][2]);
            const float go = gates_sh[b * 65 + 48 + u] + blo((unsigned)xv[p][3]);
            const float ig = 1.f / (1.f + __expf(-gi));
            const float fg = 1.f / (1.f + __expf(-gf));
            const float g2 = tanhf(gg);
            const float og = 1.f / (1.f + __expf(-go));
            const float cn = fg * c_sh[b * 17 + u] + ig * g2;
            c_sh[b * 17 + u] = cn;
            hs[((size_t)b * NS + t) * NH + j0 + u] = f2bf(og * tanhf(cn));
        }

        // -- grid barrier: release h_t, acquire for step t+1 --
        __threadfence();                     // publish h_t (device scope)
        __syncthreads();
        if (tid == 0) {
            unsigned g = __hip_atomic_load(&bar[1], __ATOMIC_RELAXED, __HIP_MEMORY_SCOPE_AGENT);
            unsigned a = __hip_atomic_fetch_add(&bar[0], 1u, __ATOMIC_ACQ_REL, __HIP_MEMORY_SCOPE_AGENT);
            if (a == LSTM_BLOCKS - 1) {
                __hip_atomic_store(&bar[0], 0u, __ATOMIC_RELAXED, __HIP_MEMORY_SCOPE_AGENT);
                __hip_atomic_store(&bar[1], g + 1u, __ATOMIC_RELEASE, __HIP_MEMORY_SCOPE_AGENT);
            } else {
                while (__hip_atomic_load(&bar[1], __ATOMIC_RELAXED, __HIP_MEMORY_SCOPE_AGENT) == g)
                    __builtin_amdgcn_s_sleep(2);
            }
        }
        __syncthreads();
        __threadfence();                     // acquire: invalidate stale L1/L2
    }
}

// =====================================================================
// GEMM3: out[m, v] = hs[m,:] . W_fc[v,:] + b_fc[v]   (unchanged — verified)
// =====================================================================
__global__ __launch_bounds__(256) void k_logits_gemm(
    const unsigned short* __restrict__ hs,   // bf16
    const float* __restrict__ W_fc,          // fp32
    const float* __restrict__ b_fc,          // fp32
    float* __restrict__ out)                 // fp32
{
    constexpr int BK = 32, LDP = BK + 8;
    __shared__ __align__(16) unsigned short Ash[64 * LDP];
    __shared__ __align__(16) unsigned short Bsh[64 * LDP];

    const int tid = threadIdx.x;
    const int m0 = blockIdx.y * 64;
    const int n0 = blockIdx.x * 64;

    const int wave = tid >> 6, lane = tid & 63;
    const int wm = (wave >> 1) * 32, wn = (wave & 1) * 32;
    const int fr = lane & 15, kq = lane >> 4;

    const int sr = tid >> 2;
    const int sc = (tid & 3) * 8;
    const int brow = min(n0 + sr, NV - 1);

    f32x4 acc[2][2] = {};

    for (int k0 = 0; k0 < NH; k0 += BK) {
        const float* bp = W_fc + (size_t)brow * NH + k0 + sc;
        float4 bf0 = *(const float4*)bp, bf1 = *(const float4*)(bp + 4);
        *(uint4*)(Ash + sr * LDP + sc) =
            *(const uint4*)(hs + (size_t)(m0 + sr) * NH + k0 + sc);
        *(uint4*)(Bsh + sr * LDP + sc) = pack8(bf0, bf1);
        __syncthreads();
        bf16x8 a0 = *(const bf16x8*)(Ash + (wm + fr) * LDP + kq * 8);
        bf16x8 a1 = *(const bf16x8*)(Ash + (wm + 16 + fr) * LDP + kq * 8);
        bf16x8 b0 = *(const bf16x8*)(Bsh + (wn + fr) * LDP + kq * 8);
        bf16x8 b1 = *(const bf16x8*)(Bsh + (wn + 16 + fr) * LDP + kq * 8);
        acc[0][0] = __builtin_amdgcn_mfma_f32_16x16x32_bf16(a0, b0, acc[0][0], 0, 0, 0);
        acc[0][1] = __builtin_amdgcn_mfma_f32_16x16x32_bf16(a0, b1, acc[0][1], 0, 0, 0);
        acc[1][0] = __builtin_amdgcn_mfma_f32_16x16x32_bf16(a1, b0, acc[1][0], 0, 0, 0);
        acc[1][1] = __builtin_amdgcn_mfma_f32_16x16x32_bf16(a1, b1, acc[1][1], 0, 0, 0);
        __syncthreads();
    }

    for (int i = 0; i < 2; ++i)
        for (int j = 0; j < 2; ++j) {
            const int row = m0 + wm + i * 16 + kq * 4;
            const int col = n0 + wn + j * 16 + fr;
            if (col < NV) {
                const float bias = b_fc[col];
                for (int r = 0; r < 4; ++r)
                    out[(size_t)(row + r) * NV + col] = acc[i][j][r] + bias;
            }
        }
}

// =====================================================================
extern "C" void kernel_launch(void* const* d_in, const int* in_sizes, int n_in,
                              void* d_out, int out_size, void* d_ws, size_t ws_size,
                              hipStream_t stream)
{
    const int*   x    = (const int*)d_in[0];
    const float* emb  = (const float*)d_in[1];
    const float* W_ih = (const float*)d_in[2];
    const float* W_hh = (const float*)d_in[3];
    const float* b_ih = (const float*)d_in[4];
    const float* b_hh = (const float*)d_in[5];
    const float* W_fc = (const float*)d_in[6];
    const float* b_fc = (const float*)d_in[7];
    float*       out  = (float*)d_out;

    // workspace: xg bf16 (134.2MB) | hs bf16 (33.6MB) | barrier (8B)
    char* w = (char*)d_ws;
    const size_t XG_BYTES = (size_t)NB * NS * NG * 2;
    const size_t HS_BYTES = (size_t)NB * NS * NH * 2;
    unsigned short* xg  = (unsigned short*)w;
    unsigned short* hsb = (unsigned short*)(w + XG_BYTES);
    unsigned*       bar = (unsigned*)(w + XG_BYTES + HS_BYTES);

    hipMemsetAsync(bar, 0, 2 * sizeof(unsigned), stream);

    k_embed_gemm<<<dim3(NG / 64, (NB * NS) / 64), 256, 0, stream>>>(
        x, emb, W_ih, b_ih, b_hh, xg);

    k_lstm_persist<<<dim3(LSTM_BLOCKS), 256, 0, stream>>>(xg, W_hh, hsb, bar);

    k_logits_gemm<<<dim3((NV + 63) / 64, (NB * NS) / 64), 256, 0, stream>>>(
        hsb, W_fc, b_fc, out);
}

// Round 4
// 4561.736 us; speedup vs baseline: 2.5371x; 2.5371x over previous
//
#include <hip/hip_runtime.h>
#include <hip/hip_bf16.h>

using bf16x8 = __attribute__((ext_vector_type(8))) __bf16;
using f32x4  = __attribute__((ext_vector_type(4))) float;

constexpr int NB = 32;     // batch
constexpr int NS = 512;    // seq len
constexpr int NE = 512;    // embed dim
constexpr int NH = 1024;   // hidden
constexpr int NV = 5000;   // vocab
constexpr int NG = 4096;   // 4*NH (gates: i,f,g,o)

constexpr int LSTM_BLOCKS = 64;   // persistent scan: 64 blocks x 16 hidden units

// ---------- bf16 helpers (raw ushort storage) ----------
__device__ __forceinline__ float blo(unsigned u) {
    union { unsigned i; float f; } v; v.i = u << 16; return v.f;
}
__device__ __forceinline__ unsigned short f2bf(float f) {  // round-to-nearest-even
    union { float f; unsigned i; } v; v.f = f;
    unsigned r = v.i + 0x7fffu + ((v.i >> 16) & 1u);
    return (unsigned short)(r >> 16);
}
// pack 8 fp32 -> 8 bf16 (as uint4, shorts in index order, little-endian)
__device__ __forceinline__ uint4 pack8(float4 a, float4 b) {
    uint4 r;
    r.x = (unsigned)f2bf(a.x) | ((unsigned)f2bf(a.y) << 16);
    r.y = (unsigned)f2bf(a.z) | ((unsigned)f2bf(a.w) << 16);
    r.z = (unsigned)f2bf(b.x) | ((unsigned)f2bf(b.y) << 16);
    r.w = (unsigned)f2bf(b.z) | ((unsigned)f2bf(b.w) << 16);
    return r;
}

// ---------- device-coherent (LLC, bypass per-XCD L1/L2) access ----------
__device__ __forceinline__ uint4 load_b128_llc(const void* p) {
    uint4 r;
    asm volatile("global_load_dwordx4 %0, %1, off sc0 sc1" : "=v"(r) : "v"(p));
    return r;
}
__device__ __forceinline__ void store_short_llc(void* p, unsigned v) {
    asm volatile("global_store_short %0, %1, off sc0 sc1" :: "v"(p), "v"(v) : "memory");
}
__device__ __forceinline__ void wait_vm0() {
    asm volatile("s_waitcnt vmcnt(0)" ::: "memory");
}

// =====================================================================
// GEMM1: xgT[s][g][jblk][b][u] = emb[x[b*S+s]] . W_ih^T + b_ih + b_hh
// Transposed output layout so the scan's xg reads are fully coalesced.
// =====================================================================
__global__ __launch_bounds__(256) void k_embed_gemm(
    const int* __restrict__ x,
    const float* __restrict__ emb,
    const float* __restrict__ W_ih,
    const float* __restrict__ b_ih,
    const float* __restrict__ b_hh,
    unsigned short* __restrict__ xgT)
{
    constexpr int BK = 32, LDP = BK + 8;
    __shared__ __align__(16) unsigned short Ash[64 * LDP];
    __shared__ __align__(16) unsigned short Bsh[64 * LDP];
    __shared__ int ids[64];

    const int tid = threadIdx.x;
    const int m0 = blockIdx.y * 64;
    const int n0 = blockIdx.x * 64;
    if (tid < 64) ids[tid] = x[m0 + tid];
    __syncthreads();

    const int wave = tid >> 6, lane = tid & 63;
    const int wm = (wave >> 1) * 32, wn = (wave & 1) * 32;
    const int fr = lane & 15, kq = lane >> 4;

    const int sr = tid >> 2;
    const int sc = (tid & 3) * 8;

    f32x4 acc[2][2] = {};

    for (int k0 = 0; k0 < NE; k0 += BK) {
        const float* ap = emb + (size_t)ids[sr] * NE + k0 + sc;
        const float* bp = W_ih + (size_t)(n0 + sr) * NE + k0 + sc;
        float4 af0 = *(const float4*)ap, af1 = *(const float4*)(ap + 4);
        float4 bf0 = *(const float4*)bp, bf1 = *(const float4*)(bp + 4);
        *(uint4*)(Ash + sr * LDP + sc) = pack8(af0, af1);
        *(uint4*)(Bsh + sr * LDP + sc) = pack8(bf0, bf1);
        __syncthreads();
        bf16x8 a0 = *(const bf16x8*)(Ash + (wm + fr) * LDP + kq * 8);
        bf16x8 a1 = *(const bf16x8*)(Ash + (wm + 16 + fr) * LDP + kq * 8);
        bf16x8 b0 = *(const bf16x8*)(Bsh + (wn + fr) * LDP + kq * 8);
        bf16x8 b1 = *(const bf16x8*)(Bsh + (wn + 16 + fr) * LDP + kq * 8);
        acc[0][0] = __builtin_amdgcn_mfma_f32_16x16x32_bf16(a0, b0, acc[0][0], 0, 0, 0);
        acc[0][1] = __builtin_amdgcn_mfma_f32_16x16x32_bf16(a0, b1, acc[0][1], 0, 0, 0);
        acc[1][0] = __builtin_amdgcn_mfma_f32_16x16x32_bf16(a1, b0, acc[1][0], 0, 0, 0);
        acc[1][1] = __builtin_amdgcn_mfma_f32_16x16x32_bf16(a1, b1, acc[1][1], 0, 0, 0);
        __syncthreads();
    }

    for (int i = 0; i < 2; ++i)
        for (int j = 0; j < 2; ++j) {
            const int row = m0 + wm + i * 16 + kq * 4;     // m = b*NS + s
            const int col = n0 + wn + j * 16 + fr;         // col = g*NH + jblk*16 + u
            const int g = col >> 10, jblk = (col >> 4) & 63, u = col & 15;
            const float bias = b_ih[col] + b_hh[col];
            for (int r = 0; r < 4; ++r) {
                const int m = row + r, b = m >> 9, s = m & 511;
                xgT[((((size_t)s * 4 + g) * 64 + jblk) * 32 + b) * 16 + u] =
                    f2bf(acc[i][j][r] + bias);
            }
        }
}

// =====================================================================
// Persistent LSTM scan — fence-free coherence, no extra h buffer:
//  - hs[B,S,H] is naturally double-buffered by t: step t writes hs[:,t,:],
//    step t+1 reads hs[:,t-1,:] (disjoint) -> no ping-pong needed.
//  - hs written AND staged with sc0/sc1 (LLC-coherent, bypasses the
//    non-coherent per-XCD L2s) -> NO __threadfence / cache maintenance.
//  - grid barrier: MONOTONIC arrival counter (never reset -> no clobber
//    race), release store of generation; bounded spin failsafe.
//  - bar lives at XG+HS (inside the verified workspace footprint).
//  - W_hh slice register-resident (loaded once); c in LDS; xgT coalesced.
// =====================================================================
__global__ __launch_bounds__(256, 1) void k_lstm_persist(
    const unsigned short* __restrict__ xgT,  // bf16 [S][4][64][32][16]
    const float* __restrict__ W_hh,          // fp32 [4H,H]
    unsigned short* __restrict__ hs,         // bf16 [B,S,H] (sc0sc1 everywhere)
    unsigned* __restrict__ bar)              // bar[0]=arrivals (monotonic), bar[1]=generation
{
    __shared__ __align__(16) unsigned short h_sh[32 * 1024];  // 64 KB, swizzled
    __shared__ float gates_sh[32 * 65];                       // [b][col] pad65
    __shared__ float c_sh[32 * 17];                           // persistent cell state

    const int tid  = threadIdx.x;
    const int wave = tid >> 6, lane = tid & 63;
    const int fr = lane & 15, kq = lane >> 4;
    const int bid = blockIdx.x;
    const int j0 = bid * 16;                 // this block's 16 hidden units

    // ---- register-resident W_hh (bf16): wave = gate, lane col fr = unit ----
    bf16x8 bfrag[32];
    {
        const float* wrow = W_hh + (size_t)(wave * NH + j0 + fr) * NH;
#pragma unroll
        for (int ks = 0; ks < 32; ++ks) {
            const float* wp = wrow + ks * 32 + kq * 8;
            float4 w0 = *(const float4*)wp, w1 = *(const float4*)(wp + 4);
            uint4 pk = pack8(w0, w1);
            bfrag[ks] = *(bf16x8*)&pk;
        }
    }

    // ---- zero h_sh (h_{-1}=0) and c ----
    {
        uint4 z = {0, 0, 0, 0};
#pragma unroll
        for (int r = 0; r < 16; ++r)
            *(uint4*)((char*)h_sh + r * 4096 + tid * 16) = z;
        for (int i = tid; i < 32 * 17; i += 256) c_sh[i] = 0.f;
    }
    __syncthreads();

    const int srow = tid >> 7;     // staging: waves 0/1 -> even b, 2/3 -> odd b
    const int sc16 = tid & 127;    // 16B chunk within a 2048B row
    const int swz  = (fr & 7) << 4;
    const int au = tid & 15;       // activation mapping: u-minor (coalesced)
    const int ab = tid >> 4;       // b base (p adds 16)

    for (int t = 0; t < NS; ++t) {
        // -- xg prefetch: fully coalesced from xgT (plain loads, read-once) --
        unsigned short xv[2][4];
#pragma unroll
        for (int p = 0; p < 2; ++p) {
            const int b = ab + p * 16;
            const unsigned short* xp =
                xgT + ((((size_t)t * 4) * 64 + bid) * 32 + b) * 16 + au;
#pragma unroll
            for (int g = 0; g < 4; ++g) xv[p][g] = xp[(size_t)g * (64 * 32 * 16)];
        }

        // -- stage h_{t-1} from hs (LLC-coherent) into swizzled LDS --
        if (t > 0) {
            uint4 stg[16];
#pragma unroll
            for (int r = 0; r < 16; ++r) {
                const int b = r * 2 + srow;
                stg[r] = load_b128_llc(hs + ((size_t)b * NS + (t - 1)) * NH + sc16 * 8);
            }
            wait_vm0();
            __builtin_amdgcn_sched_barrier(0);
#pragma unroll
            for (int r = 0; r < 16; ++r) {
                const int b = r * 2 + srow;
                int off = b * 2048 + sc16 * 16;
                off ^= (b & 7) << 4;                     // same XOR as read side
                *(uint4*)((char*)h_sh + off) = stg[r];
            }
        }
        __syncthreads();

        // -- gates = h_{t-1} @ W_hh_slice^T  (full K=1024, no reduction) --
        f32x4 acc0 = {}, acc1 = {};
#pragma unroll
        for (int ks = 0; ks < 32; ++ks) {
            const int cb = ks * 64 + kq * 16;
            bf16x8 a0 = *(const bf16x8*)((const char*)h_sh + ((fr * 2048 + cb) ^ swz));
            bf16x8 a1 = *(const bf16x8*)((const char*)h_sh + (((fr + 16) * 2048 + cb) ^ swz));
            acc0 = __builtin_amdgcn_mfma_f32_16x16x32_bf16(a0, bfrag[ks], acc0, 0, 0, 0);
            acc1 = __builtin_amdgcn_mfma_f32_16x16x32_bf16(a1, bfrag[ks], acc1, 0, 0, 0);
        }

        // C/D layout: row(batch) = kq*4+r, col = fr; wave w -> cols w*16..w*16+15
#pragma unroll
        for (int r = 0; r < 4; ++r) {
            gates_sh[(kq * 4 + r) * 65 + wave * 16 + fr]      = acc0[r];
            gates_sh[(16 + kq * 4 + r) * 65 + wave * 16 + fr] = acc1[r];
        }
        __syncthreads();

        // -- activations + state update: 512 items = 32 b x 16 u, u-minor --
#pragma unroll
        for (int p = 0; p < 2; ++p) {
            const int b = ab + p * 16, u = au;
            const float gi = gates_sh[b * 65 +      u] + blo((unsigned)xv[p][0]);
            const float gf = gates_sh[b * 65 + 16 + u] + blo((unsigned)xv[p][1]);
            const float gg = gates_sh[b * 65 + 32 + u] + blo((unsigned)xv[p][2]);
            const float go = gates_sh[b * 65 + 48 + u] + blo((unsigned)xv[p][3]);
            const float ig = 1.f / (1.f + __expf(-gi));
            const float fg = 1.f / (1.f + __expf(-gf));
            const float g2 = tanhf(gg);
            const float og = 1.f / (1.f + __expf(-go));
            const float cn = fg * c_sh[b * 17 + u] + ig * g2;
            c_sh[b * 17 + u] = cn;
            const unsigned short hv = f2bf(og * tanhf(cn));
            store_short_llc(hs + ((size_t)b * NS + t) * NH + j0 + u, (unsigned)hv);
        }

        // -- grid barrier: monotonic arrivals, generation release --
        wait_vm0();                          // hs stores acked at LLC
        __syncthreads();                     // all waves drained & arrived
        if (tid == 0) {
            unsigned a = __hip_atomic_fetch_add(&bar[0], 1u, __ATOMIC_RELAXED,
                                                __HIP_MEMORY_SCOPE_AGENT);
            if (a == (unsigned)(LSTM_BLOCKS * (t + 1) - 1)) {
                __hip_atomic_store(&bar[1], (unsigned)(t + 1), __ATOMIC_RELEASE,
                                   __HIP_MEMORY_SCOPE_AGENT);
            } else {
                int spins = 0;
                while (__hip_atomic_load(&bar[1], __ATOMIC_RELAXED,
                                         __HIP_MEMORY_SCOPE_AGENT) < (unsigned)(t + 1)) {
                    __builtin_amdgcn_s_sleep(2);
                    if (++spins > 100000) break;         // failsafe: fail loud, not hung
                }
            }
        }
        __syncthreads();
        __builtin_amdgcn_sched_barrier(0);
    }
}

// =====================================================================
// GEMM3: out[m, v] = hs[m,:] . W_fc[v,:] + b_fc[v]
// (plain cached loads of hs: sc0sc1 stores landed at LLC; L2 misses
//  fetch from LLC -> correct across the kernel boundary)
// =====================================================================
__global__ __launch_bounds__(256) void k_logits_gemm(
    const unsigned short* __restrict__ hs,   // bf16
    const float* __restrict__ W_fc,          // fp32
    const float* __restrict__ b_fc,          // fp32
    float* __restrict__ out)                 // fp32
{
    constexpr int BK = 32, LDP = BK + 8;
    __shared__ __align__(16) unsigned short Ash[64 * LDP];
    __shared__ __align__(16) unsigned short Bsh[64 * LDP];

    const int tid = threadIdx.x;
    const int m0 = blockIdx.y * 64;
    const int n0 = blockIdx.x * 64;

    const int wave = tid >> 6, lane = tid & 63;
    const int wm = (wave >> 1) * 32, wn = (wave & 1) * 32;
    const int fr = lane & 15, kq = lane >> 4;

    const int sr = tid >> 2;
    const int sc = (tid & 3) * 8;
    const int brow = min(n0 + sr, NV - 1);

    f32x4 acc[2][2] = {};

    for (int k0 = 0; k0 < NH; k0 += BK) {
        const float* bp = W_fc + (size_t)brow * NH + k0 + sc;
        float4 bf0 = *(const float4*)bp, bf1 = *(const float4*)(bp + 4);
        *(uint4*)(Ash + sr * LDP + sc) =
            *(const uint4*)(hs + (size_t)(m0 + sr) * NH + k0 + sc);
        *(uint4*)(Bsh + sr * LDP + sc) = pack8(bf0, bf1);
        __syncthreads();
        bf16x8 a0 = *(const bf16x8*)(Ash + (wm + fr) * LDP + kq * 8);
        bf16x8 a1 = *(const bf16x8*)(Ash + (wm + 16 + fr) * LDP + kq * 8);
        bf16x8 b0 = *(const bf16x8*)(Bsh + (wn + fr) * LDP + kq * 8);
        bf16x8 b1 = *(const bf16x8*)(Bsh + (wn + 16 + fr) * LDP + kq * 8);
        acc[0][0] = __builtin_amdgcn_mfma_f32_16x16x32_bf16(a0, b0, acc[0][0], 0, 0, 0);
        acc[0][1] = __builtin_amdgcn_mfma_f32_16x16x32_bf16(a0, b1, acc[0][1], 0, 0, 0);
        acc[1][0] = __builtin_amdgcn_mfma_f32_16x16x32_bf16(a1, b0, acc[1][0], 0, 0, 0);
        acc[1][1] = __builtin_amdgcn_mfma_f32_16x16x32_bf16(a1, b1, acc[1][1], 0, 0, 0);
        __syncthreads();
    }

    for (int i = 0; i < 2; ++i)
        for (int j = 0; j < 2; ++j) {
            const int row = m0 + wm + i * 16 + kq * 4;
            const int col = n0 + wn + j * 16 + fr;
            if (col < NV) {
                const float bias = b_fc[col];
                for (int r = 0; r < 4; ++r)
                    out[(size_t)(row + r) * NV + col] = acc[i][j][r] + bias;
            }
        }
}

// =====================================================================
extern "C" void kernel_launch(void* const* d_in, const int* in_sizes, int n_in,
                              void* d_out, int out_size, void* d_ws, size_t ws_size,
                              hipStream_t stream)
{
    const int*   x    = (const int*)d_in[0];
    const float* emb  = (const float*)d_in[1];
    const float* W_ih = (const float*)d_in[2];
    const float* W_hh = (const float*)d_in[3];
    const float* b_ih = (const float*)d_in[4];
    const float* b_hh = (const float*)d_in[5];
    const float* W_fc = (const float*)d_in[6];
    const float* b_fc = (const float*)d_in[7];
    float*       out  = (float*)d_out;

    // workspace: xgT bf16 (134.2MB) | hs bf16 (33.6MB) | bar (8B, in old c slot)
    char* w = (char*)d_ws;
    const size_t XG_BYTES = (size_t)NB * NS * NG * 2;
    const size_t HS_BYTES = (size_t)NB * NS * NH * 2;
    unsigned short* xgT = (unsigned short*)w;
    unsigned short* hsb = (unsigned short*)(w + XG_BYTES);
    unsigned*       bar = (unsigned*)(w + XG_BYTES + HS_BYTES);

    hipMemsetAsync(bar, 0, 2 * sizeof(unsigned), stream);

    k_embed_gemm<<<dim3(NG / 64, (NB * NS) / 64), 256, 0, stream>>>(
        x, emb, W_ih, b_ih, b_hh, xgT);

    k_lstm_persist<<<dim3(LSTM_BLOCKS), 256, 0, stream>>>(xgT, W_hh, hsb, bar);

    k_logits_gemm<<<dim3((NV + 63) / 64, (NB * NS) / 64), 256, 0, stream>>>(
        hsb, W_fc, b_fc, out);
}

// Round 5
// 4015.764 us; speedup vs baseline: 2.8820x; 1.1360x over previous
//
#include <hip/hip_runtime.h>
#include <hip/hip_bf16.h>

using bf16x8 = __attribute__((ext_vector_type(8))) __bf16;
using f32x4  = __attribute__((ext_vector_type(4))) float;

constexpr int NB = 32;     // batch
constexpr int NS = 512;    // seq len
constexpr int NE = 512;    // embed dim
constexpr int NH = 1024;   // hidden
constexpr int NV = 5000;   // vocab
constexpr int NG = 4096;   // 4*NH (gates: i,f,g,o)

constexpr int LSTM_BLOCKS = 64;   // persistent scan: 64 blocks x 16 hidden units

// ---------- bf16 helpers (raw ushort storage) ----------
__device__ __forceinline__ float blo(unsigned u) {
    union { unsigned i; float f; } v; v.i = u << 16; return v.f;
}
__device__ __forceinline__ unsigned short f2bf(float f) {  // round-to-nearest-even
    union { float f; unsigned i; } v; v.f = f;
    unsigned r = v.i + 0x7fffu + ((v.i >> 16) & 1u);
    return (unsigned short)(r >> 16);
}
// pack 8 fp32 -> 8 bf16 (as uint4, shorts in index order, little-endian)
__device__ __forceinline__ uint4 pack8(float4 a, float4 b) {
    uint4 r;
    r.x = (unsigned)f2bf(a.x) | ((unsigned)f2bf(a.y) << 16);
    r.y = (unsigned)f2bf(a.z) | ((unsigned)f2bf(a.w) << 16);
    r.z = (unsigned)f2bf(b.x) | ((unsigned)f2bf(b.y) << 16);
    r.w = (unsigned)f2bf(b.z) | ((unsigned)f2bf(b.w) << 16);
    return r;
}

// ---------- device-coherent (LLC, bypass per-XCD L1/L2) access ----------
__device__ __forceinline__ uint4 load_b128_llc(const void* p) {
    uint4 r;
    asm volatile("global_load_dwordx4 %0, %1, off sc0 sc1" : "=v"(r) : "v"(p));
    return r;
}
__device__ __forceinline__ void store_short_llc(void* p, unsigned v) {
    asm volatile("global_store_short %0, %1, off sc0 sc1" :: "v"(p), "v"(v) : "memory");
}
__device__ __forceinline__ void wait_vm0() {
    asm volatile("s_waitcnt vmcnt(0)" ::: "memory");
}

// =====================================================================
// GEMM1: xgT[s][g][jblk][b][u] = emb[x[b*S+s]] . W_ih^T + b_ih + b_hh
// Transposed output layout so the scan's xg reads are fully coalesced.
// (unchanged — verified R4)
// =====================================================================
__global__ __launch_bounds__(256) void k_embed_gemm(
    const int* __restrict__ x,
    const float* __restrict__ emb,
    const float* __restrict__ W_ih,
    const float* __restrict__ b_ih,
    const float* __restrict__ b_hh,
    unsigned short* __restrict__ xgT)
{
    constexpr int BK = 32, LDP = BK + 8;
    __shared__ __align__(16) unsigned short Ash[64 * LDP];
    __shared__ __align__(16) unsigned short Bsh[64 * LDP];
    __shared__ int ids[64];

    const int tid = threadIdx.x;
    const int m0 = blockIdx.y * 64;
    const int n0 = blockIdx.x * 64;
    if (tid < 64) ids[tid] = x[m0 + tid];
    __syncthreads();

    const int wave = tid >> 6, lane = tid & 63;
    const int wm = (wave >> 1) * 32, wn = (wave & 1) * 32;
    const int fr = lane & 15, kq = lane >> 4;

    const int sr = tid >> 2;
    const int sc = (tid & 3) * 8;

    f32x4 acc[2][2] = {};

    for (int k0 = 0; k0 < NE; k0 += BK) {
        const float* ap = emb + (size_t)ids[sr] * NE + k0 + sc;
        const float* bp = W_ih + (size_t)(n0 + sr) * NE + k0 + sc;
        float4 af0 = *(const float4*)ap, af1 = *(const float4*)(ap + 4);
        float4 bf0 = *(const float4*)bp, bf1 = *(const float4*)(bp + 4);
        *(uint4*)(Ash + sr * LDP + sc) = pack8(af0, af1);
        *(uint4*)(Bsh + sr * LDP + sc) = pack8(bf0, bf1);
        __syncthreads();
        bf16x8 a0 = *(const bf16x8*)(Ash + (wm + fr) * LDP + kq * 8);
        bf16x8 a1 = *(const bf16x8*)(Ash + (wm + 16 + fr) * LDP + kq * 8);
        bf16x8 b0 = *(const bf16x8*)(Bsh + (wn + fr) * LDP + kq * 8);
        bf16x8 b1 = *(const bf16x8*)(Bsh + (wn + 16 + fr) * LDP + kq * 8);
        acc[0][0] = __builtin_amdgcn_mfma_f32_16x16x32_bf16(a0, b0, acc[0][0], 0, 0, 0);
        acc[0][1] = __builtin_amdgcn_mfma_f32_16x16x32_bf16(a0, b1, acc[0][1], 0, 0, 0);
        acc[1][0] = __builtin_amdgcn_mfma_f32_16x16x32_bf16(a1, b0, acc[1][0], 0, 0, 0);
        acc[1][1] = __builtin_amdgcn_mfma_f32_16x16x32_bf16(a1, b1, acc[1][1], 0, 0, 0);
        __syncthreads();
    }

    for (int i = 0; i < 2; ++i)
        for (int j = 0; j < 2; ++j) {
            const int row = m0 + wm + i * 16 + kq * 4;     // m = b*NS + s
            const int col = n0 + wn + j * 16 + fr;         // col = g*NH + jblk*16 + u
            const int g = col >> 10, jblk = (col >> 4) & 63, u = col & 15;
            const float bias = b_ih[col] + b_hh[col];
            for (int r = 0; r < 4; ++r) {
                const int m = row + r, b = m >> 9, s = m & 511;
                xgT[((((size_t)s * 4 + g) * 64 + jblk) * 32 + b) * 16 + u] =
                    f2bf(acc[i][j][r] + bias);
            }
        }
}

// =====================================================================
// Persistent LSTM scan — flag-array barrier (no RMW serialization):
//  - hs[B,S,H] naturally double-buffered by t; sc0/sc1 everywhere -> no
//    cache-maintenance fences.
//  - barrier: block bid release-stores flags[bid*16]=t+1 (own cacheline);
//    wave 0's 64 lanes each poll one flag, __all ballot -> parallel
//    detection, no atomics-RMW, no sleep quantization. Monotonic flags.
//  - xg double-buffered across iterations: t+1 prefetch issued right
//    after the flag store (hides HBM latency under the barrier wait),
//    so the h-stage vmcnt drain never waits on HBM.
// =====================================================================
__global__ __launch_bounds__(256, 1) void k_lstm_persist(
    const unsigned short* __restrict__ xgT,  // bf16 [S][4][64][32][16]
    const float* __restrict__ W_hh,          // fp32 [4H,H]
    unsigned short* __restrict__ hs,         // bf16 [B,S,H] (sc0sc1 everywhere)
    unsigned* __restrict__ flags)            // [64] monotonic step flags, 64B stride
{
    __shared__ __align__(16) unsigned short h_sh[32 * 1024];  // 64 KB, swizzled
    __shared__ float gates_sh[32 * 65];                       // [b][col] pad65
    __shared__ float c_sh[32 * 17];                           // persistent cell state

    const int tid  = threadIdx.x;
    const int wave = tid >> 6, lane = tid & 63;
    const int fr = lane & 15, kq = lane >> 4;
    const int bid = blockIdx.x;
    const int j0 = bid * 16;                 // this block's 16 hidden units

    // ---- register-resident W_hh (bf16): wave = gate, lane col fr = unit ----
    bf16x8 bfrag[32];
    {
        const float* wrow = W_hh + (size_t)(wave * NH + j0 + fr) * NH;
#pragma unroll
        for (int ks = 0; ks < 32; ++ks) {
            const float* wp = wrow + ks * 32 + kq * 8;
            float4 w0 = *(const float4*)wp, w1 = *(const float4*)(wp + 4);
            uint4 pk = pack8(w0, w1);
            bfrag[ks] = *(bf16x8*)&pk;
        }
    }

    // ---- zero h_sh (h_{-1}=0) and c ----
    {
        uint4 z = {0, 0, 0, 0};
#pragma unroll
        for (int r = 0; r < 16; ++r)
            *(uint4*)((char*)h_sh + r * 4096 + tid * 16) = z;
        for (int i = tid; i < 32 * 17; i += 256) c_sh[i] = 0.f;
    }
    __syncthreads();

    const int srow = tid >> 7;     // staging: waves 0/1 -> even b, 2/3 -> odd b
    const int sc16 = tid & 127;    // 16B chunk within a 2048B row
    const int swz  = (fr & 7) << 4;
    const int au = tid & 15;       // activation mapping: u-minor (coalesced)
    const int ab = tid >> 4;       // b base (p adds 16)

    // ---- xg double-buffer: prefetch t=0 ----
    unsigned short xv[2][4], xn[2][4];
#pragma unroll
    for (int p = 0; p < 2; ++p) {
        const int b = ab + p * 16;
        const unsigned short* xp = xgT + (((size_t)0 * 4 * 64 + bid) * 32 + b) * 16 + au;
#pragma unroll
        for (int g = 0; g < 4; ++g) xv[p][g] = xp[(size_t)g * (64 * 32 * 16)];
    }

    for (int t = 0; t < NS; ++t) {
        // -- stage h_{t-1} from hs (LLC-coherent) into swizzled LDS --
        if (t > 0) {
            uint4 stg[16];
#pragma unroll
            for (int r = 0; r < 16; ++r) {
                const int b = r * 2 + srow;
                stg[r] = load_b128_llc(hs + ((size_t)b * NS + (t - 1)) * NH + sc16 * 8);
            }
            wait_vm0();
            __builtin_amdgcn_sched_barrier(0);
#pragma unroll
            for (int r = 0; r < 16; ++r) {
                const int b = r * 2 + srow;
                int off = b * 2048 + sc16 * 16;
                off ^= (b & 7) << 4;                     // same XOR as read side
                *(uint4*)((char*)h_sh + off) = stg[r];
            }
        }
        __syncthreads();

        // -- gates = h_{t-1} @ W_hh_slice^T  (full K=1024, no reduction) --
        f32x4 acc0 = {}, acc1 = {};
#pragma unroll
        for (int ks = 0; ks < 32; ++ks) {
            const int cb = ks * 64 + kq * 16;
            bf16x8 a0 = *(const bf16x8*)((const char*)h_sh + ((fr * 2048 + cb) ^ swz));
            bf16x8 a1 = *(const bf16x8*)((const char*)h_sh + (((fr + 16) * 2048 + cb) ^ swz));
            acc0 = __builtin_amdgcn_mfma_f32_16x16x32_bf16(a0, bfrag[ks], acc0, 0, 0, 0);
            acc1 = __builtin_amdgcn_mfma_f32_16x16x32_bf16(a1, bfrag[ks], acc1, 0, 0, 0);
        }

        // C/D layout: row(batch) = kq*4+r, col = fr; wave w -> cols w*16..w*16+15
#pragma unroll
        for (int r = 0; r < 4; ++r) {
            gates_sh[(kq * 4 + r) * 65 + wave * 16 + fr]      = acc0[r];
            gates_sh[(16 + kq * 4 + r) * 65 + wave * 16 + fr] = acc1[r];
        }
        __syncthreads();

        // -- activations + state update: 512 items = 32 b x 16 u, u-minor --
#pragma unroll
        for (int p = 0; p < 2; ++p) {
            const int b = ab + p * 16, u = au;
            const float gi = gates_sh[b * 65 +      u] + blo((unsigned)xv[p][0]);
            const float gf = gates_sh[b * 65 + 16 + u] + blo((unsigned)xv[p][1]);
            const float gg = gates_sh[b * 65 + 32 + u] + blo((unsigned)xv[p][2]);
            const float go = gates_sh[b * 65 + 48 + u] + blo((unsigned)xv[p][3]);
            const float ig = 1.f / (1.f + __expf(-gi));
            const float fg = 1.f / (1.f + __expf(-gf));
            const float g2 = tanhf(gg);
            const float og = 1.f / (1.f + __expf(-go));
            const float cn = fg * c_sh[b * 17 + u] + ig * g2;
            c_sh[b * 17 + u] = cn;
            const unsigned short hv = f2bf(og * tanhf(cn));
            store_short_llc(hs + ((size_t)b * NS + t) * NH + j0 + u, (unsigned)hv);
        }

        // -- publish: drain h stores, then release own flag --
        wait_vm0();                          // hs stores acked at LLC
        __syncthreads();                     // all waves drained
        if (tid == 0)
            __hip_atomic_store(&flags[bid * 16], (unsigned)(t + 1),
                               __ATOMIC_RELEASE, __HIP_MEMORY_SCOPE_AGENT);

        // -- prefetch xg for t+1 (in flight during the barrier wait) --
        {
            const int tn = (t + 1 < NS) ? t + 1 : t;
#pragma unroll
            for (int p = 0; p < 2; ++p) {
                const int b = ab + p * 16;
                const unsigned short* xp =
                    xgT + (((size_t)tn * 4 * 64 + bid) * 32 + b) * 16 + au;
#pragma unroll
                for (int g = 0; g < 4; ++g) xn[p][g] = xp[(size_t)g * (64 * 32 * 16)];
            }
        }

        // -- barrier wait: 64 lanes of wave 0 poll 64 flags in parallel --
        if (wave == 0) {
            const unsigned tgt = (unsigned)(t + 1);
            int spins = 0;
            for (;;) {
                unsigned f = __hip_atomic_load(&flags[lane * 16], __ATOMIC_RELAXED,
                                               __HIP_MEMORY_SCOPE_AGENT);
                if (__all(f >= tgt)) break;
                if (++spins > (1 << 20)) break;          // failsafe: fail loud
            }
        }
        __syncthreads();

        // -- commit xg double-buffer (static register copy) --
#pragma unroll
        for (int p = 0; p < 2; ++p)
#pragma unroll
            for (int g = 0; g < 4; ++g) xv[p][g] = xn[p][g];
    }
}

// =====================================================================
// Convert W_fc fp32 -> bf16 into reclaimed xgT space (runs after scan).
// =====================================================================
__global__ __launch_bounds__(256) void k_convert_wfc(
    const float* __restrict__ W_fc, unsigned short* __restrict__ W_fcb)
{
    const size_t i = ((size_t)blockIdx.x * 256 + threadIdx.x) * 8;
    float4 a = *(const float4*)(W_fc + i);
    float4 b = *(const float4*)(W_fc + i + 4);
    *(uint4*)(W_fcb + i) = pack8(a, b);
}

// =====================================================================
// GEMM3: out[m, v] = hs[m,:] . W_fcb[v,:] + b_fc[v]
// 128x128 tile, BK=32, 4 waves (2x2 of 64x64), bf16 A and B.
// =====================================================================
__global__ __launch_bounds__(256) void k_logits_gemm(
    const unsigned short* __restrict__ hs,    // bf16
    const unsigned short* __restrict__ W_fcb, // bf16 (pre-converted)
    const float* __restrict__ b_fc,           // fp32
    float* __restrict__ out)                  // fp32
{
    constexpr int BK = 32, LDP = BK + 8;
    __shared__ __align__(16) unsigned short Ash[128 * LDP];
    __shared__ __align__(16) unsigned short Bsh[128 * LDP];

    const int tid = threadIdx.x;
    const int m0 = blockIdx.y * 128;
    const int n0 = blockIdx.x * 128;

    const int wave = tid >> 6, lane = tid & 63;
    const int wm = (wave >> 1) * 64, wn = (wave & 1) * 64;
    const int fr = lane & 15, kq = lane >> 4;

    const int sr = tid >> 1;            // 0..127
    const int sc = (tid & 1) * 16;      // 0 or 16 (elements)
    const int brow = min(n0 + sr, NV - 1);

    f32x4 acc[4][4] = {};

    for (int k0 = 0; k0 < NH; k0 += BK) {
        const unsigned short* ap = hs + (size_t)(m0 + sr) * NH + k0 + sc;
        const unsigned short* bp = W_fcb + (size_t)brow * NH + k0 + sc;
        uint4 a0 = *(const uint4*)ap, a1 = *(const uint4*)(ap + 8);
        uint4 b0 = *(const uint4*)bp, b1 = *(const uint4*)(bp + 8);
        *(uint4*)(Ash + sr * LDP + sc)     = a0;
        *(uint4*)(Ash + sr * LDP + sc + 8) = a1;
        *(uint4*)(Bsh + sr * LDP + sc)     = b0;
        *(uint4*)(Bsh + sr * LDP + sc + 8) = b1;
        __syncthreads();
        bf16x8 af[4], bf[4];
#pragma unroll
        for (int i = 0; i < 4; ++i) {
            af[i] = *(const bf16x8*)(Ash + (wm + i * 16 + fr) * LDP + kq * 8);
            bf[i] = *(const bf16x8*)(Bsh + (wn + i * 16 + fr) * LDP + kq * 8);
        }
#pragma unroll
        for (int i = 0; i < 4; ++i)
#pragma unroll
            for (int j = 0; j < 4; ++j)
                acc[i][j] = __builtin_amdgcn_mfma_f32_16x16x32_bf16(af[i], bf[j], acc[i][j], 0, 0, 0);
        __syncthreads();
    }

    for (int i = 0; i < 4; ++i)
        for (int j = 0; j < 4; ++j) {
            const int row = m0 + wm + i * 16 + kq * 4;
            const int col = n0 + wn + j * 16 + fr;
            if (col < NV) {
                const float bias = b_fc[col];
                for (int r = 0; r < 4; ++r)
                    out[(size_t)(row + r) * NV + col] = acc[i][j][r] + bias;
            }
        }
}

// =====================================================================
extern "C" void kernel_launch(void* const* d_in, const int* in_sizes, int n_in,
                              void* d_out, int out_size, void* d_ws, size_t ws_size,
                              hipStream_t stream)
{
    const int*   x    = (const int*)d_in[0];
    const float* emb  = (const float*)d_in[1];
    const float* W_ih = (const float*)d_in[2];
    const float* W_hh = (const float*)d_in[3];
    const float* b_ih = (const float*)d_in[4];
    const float* b_hh = (const float*)d_in[5];
    const float* W_fc = (const float*)d_in[6];
    const float* b_fc = (const float*)d_in[7];
    float*       out  = (float*)d_out;

    // workspace: xgT bf16 (134.2MB) | hs bf16 (33.6MB) | flags (4KB, old c slot)
    // After the scan, xgT's region is reused for bf16 W_fc (10.2MB).
    char* w = (char*)d_ws;
    const size_t XG_BYTES = (size_t)NB * NS * NG * 2;
    const size_t HS_BYTES = (size_t)NB * NS * NH * 2;
    unsigned short* xgT   = (unsigned short*)w;
    unsigned short* hsb   = (unsigned short*)(w + XG_BYTES);
    unsigned*       flags = (unsigned*)(w + XG_BYTES + HS_BYTES);
    unsigned short* W_fcb = (unsigned short*)w;      // alias: valid after scan

    hipMemsetAsync(flags, 0, LSTM_BLOCKS * 64, stream);

    k_embed_gemm<<<dim3(NG / 64, (NB * NS) / 64), 256, 0, stream>>>(
        x, emb, W_ih, b_ih, b_hh, xgT);

    k_lstm_persist<<<dim3(LSTM_BLOCKS), 256, 0, stream>>>(xgT, W_hh, hsb, flags);

    k_convert_wfc<<<dim3((NV * NH) / (256 * 8)), 256, 0, stream>>>(W_fc, W_fcb);

    k_logits_gemm<<<dim3((NV + 127) / 128, (NB * NS) / 128), 256, 0, stream>>>(
        hsb, W_fcb, b_fc, out);
}